// Round 1
// baseline (1826.601 us; speedup 1.0000x reference)
//
#include <hip/hip_runtime.h>

#define B_  8
#define L_  2048
#define N_  512
#define D_  1024
#define H_  16
#define HD_ 64
#define EPS_ 1e-5f

#define NEG_INF (-__builtin_inff())

// ---------------------------------------------------------------------------
// Detect whether region_mask arrives as uint8 (numpy bool) or int32.
// If int32 little-endian 0/1 values, every byte at index%4 != 0 is zero.
// A random uint8 bool array has ~50% ones at those positions.
// ---------------------------------------------------------------------------
__global__ __launch_bounds__(256) void detect_mask_kernel(
    const unsigned char* __restrict__ m, int* __restrict__ flag) {
  __shared__ int sany;
  if (threadIdx.x == 0) sany = 0;
  __syncthreads();
  int any = 0;
  for (int i = threadIdx.x; i < B_ * N_; i += 256)
    if ((i & 3) != 0 && m[i] != 0) any = 1;
  if (any) sany = 1;  // benign race, same value
  __syncthreads();
  if (threadIdx.x == 0) *flag = sany;  // 1 => uint8 mask, 0 => int32 mask
}

// ---------------------------------------------------------------------------
// Per-row LayerNorm stats: mean and rsqrt(var+eps). One block per row, D=1024.
// ---------------------------------------------------------------------------
__global__ __launch_bounds__(256) void ln_stats_kernel(
    const float* __restrict__ X, float* __restrict__ mu, float* __restrict__ rs) {
  const int row = blockIdx.x;
  const float4 x = ((const float4*)(X + (size_t)row * D_))[threadIdx.x];
  float s  = x.x + x.y + x.z + x.w;
  float ss = x.x * x.x + x.y * x.y + x.z * x.z + x.w * x.w;
#pragma unroll
  for (int off = 32; off > 0; off >>= 1) {
    s  += __shfl_down(s, off);
    ss += __shfl_down(ss, off);
  }
  __shared__ float red[8];
  const int wid = threadIdx.x >> 6;
  if ((threadIdx.x & 63) == 0) { red[wid * 2] = s; red[wid * 2 + 1] = ss; }
  __syncthreads();
  if (threadIdx.x == 0) {
    const float S  = red[0] + red[2] + red[4] + red[6];
    const float SS = red[1] + red[3] + red[5] + red[7];
    const float m  = S * (1.0f / D_);
    const float v  = SS * (1.0f / D_) - m * m;
    mu[row] = m;
    rs[row] = rsqrtf(v + EPS_);
  }
}

// ---------------------------------------------------------------------------
// Y = op(X) @ W^T  (NT GEMM, K = N = 1024 fixed).
// LN:  op(X) = (X - mu)*rs*gamma + beta   (fused on A-tile load)
// EPI: 1 => Y += bias[col] + resid[row,col]   (final projection + residual)
// 128x128 tile, BK=32, 256 threads, 8x8 per-thread outer product.
// ---------------------------------------------------------------------------
template <bool LN, int EPI>
__global__ __launch_bounds__(256) void gemm_nt_kernel(
    const float* __restrict__ X, const float* __restrict__ W, float* __restrict__ Y,
    const float* __restrict__ mu, const float* __restrict__ rs,
    const float* __restrict__ gamma, const float* __restrict__ beta,
    const float* __restrict__ bias, const float* __restrict__ resid) {
  __shared__ float As[32][132];  // [k][m], +4 pad: 2-way (free) read conflicts
  __shared__ float Bs[32][132];  // [k][n]
  const int tid = threadIdx.x;
  const int bm = blockIdx.x, bn = blockIdx.y;
  const int tx = tid & 15, ty = tid >> 4;

  float acc[8][8];
#pragma unroll
  for (int i = 0; i < 8; i++)
#pragma unroll
    for (int j = 0; j < 8; j++) acc[i][j] = 0.f;

  for (int kt = 0; kt < 1024; kt += 32) {
    __syncthreads();
#pragma unroll
    for (int t = 0; t < 4; t++) {
      const int idx = tid + t * 256;
      const int row = idx >> 3, kv = idx & 7;
      const int gk = kt + kv * 4;
      {
        const int gr = bm * 128 + row;
        const float4 xv = *(const float4*)(X + (size_t)gr * 1024 + gk);
        float vals[4] = {xv.x, xv.y, xv.z, xv.w};
        if (LN) {
          const float m_ = mu[gr], r_ = rs[gr];
#pragma unroll
          for (int j = 0; j < 4; j++)
            vals[j] = (vals[j] - m_) * r_ * gamma[gk + j] + beta[gk + j];
        }
#pragma unroll
        for (int j = 0; j < 4; j++) As[kv * 4 + j][row] = vals[j];
      }
      {
        const int gn = bn * 128 + row;
        const float4 wv = *(const float4*)(W + (size_t)gn * 1024 + gk);
        const float vals[4] = {wv.x, wv.y, wv.z, wv.w};
#pragma unroll
        for (int j = 0; j < 4; j++) Bs[kv * 4 + j][row] = vals[j];
      }
    }
    __syncthreads();
#pragma unroll
    for (int k = 0; k < 32; k++) {
      float a[8], b[8];
      {
        const float4 t0 = *(const float4*)&As[k][ty * 4];
        const float4 t1 = *(const float4*)&As[k][64 + ty * 4];
        a[0] = t0.x; a[1] = t0.y; a[2] = t0.z; a[3] = t0.w;
        a[4] = t1.x; a[5] = t1.y; a[6] = t1.z; a[7] = t1.w;
        const float4 u0 = *(const float4*)&Bs[k][tx * 4];
        const float4 u1 = *(const float4*)&Bs[k][64 + tx * 4];
        b[0] = u0.x; b[1] = u0.y; b[2] = u0.z; b[3] = u0.w;
        b[4] = u1.x; b[5] = u1.y; b[6] = u1.z; b[7] = u1.w;
      }
#pragma unroll
      for (int i = 0; i < 8; i++)
#pragma unroll
        for (int j = 0; j < 8; j++) acc[i][j] = fmaf(a[i], b[j], acc[i][j]);
    }
  }

#pragma unroll
  for (int i = 0; i < 8; i++) {
    const int r = (i < 4) ? (ty * 4 + i) : (64 + ty * 4 + i - 4);
    const int gr = bm * 128 + r;
#pragma unroll
    for (int jh = 0; jh < 2; jh++) {
      const int gc = bn * 128 + jh * 64 + tx * 4;
      float4 o;
      o.x = acc[i][jh * 4 + 0]; o.y = acc[i][jh * 4 + 1];
      o.z = acc[i][jh * 4 + 2]; o.w = acc[i][jh * 4 + 3];
      if (EPI == 1) {
        const float4 bv = *(const float4*)(bias + gc);
        const float4 rv = *(const float4*)(resid + (size_t)gr * 1024 + gc);
        o.x += bv.x + rv.x; o.y += bv.y + rv.y;
        o.z += bv.z + rv.z; o.w += bv.w + rv.w;
      }
      *(float4*)(Y + (size_t)gr * 1024 + gc) = o;
    }
  }
}

// ---------------------------------------------------------------------------
// Flash-style masked attention. One block = (b, h, 64 q-rows).
// K staged transposed in LDS (conflict-free float4 reads), online softmax in
// registers, P redistributed via shuffles (no P buffer in LDS).
// Writes ctx[(b*L+l)*D + h*64+hd]  (same slice of the q buffer it read).
// ---------------------------------------------------------------------------
__global__ __launch_bounds__(256) void attn_kernel(
    const float* __restrict__ q, const float* __restrict__ k,
    const float* __restrict__ v, const void* __restrict__ maskp,
    const int* __restrict__ flag, float* __restrict__ ctx) {
  const int bid = blockIdx.x;
  const int qt = bid & 31;
  const int h  = (bid >> 5) & 15;
  const int b  = bid >> 9;
  const int tid = threadIdx.x;
  const int cg = tid & 15, rg = tid >> 4;
  const int c0 = cg * 4, r0 = rg * 4;

  __shared__ float Qs[64][68];   // [row][d]
  __shared__ float Kst[64][68];  // [d][j]  (transposed)
  __shared__ float Vs[64][68];   // [j][d]
  __shared__ float Msk[64];

  const size_t qbase = ((size_t)b * L_ + (size_t)qt * 64) * D_ + h * HD_;
#pragma unroll
  for (int t = 0; t < 4; t++) {
    const int idx = tid + t * 256;
    const int row = idx >> 4, dv = idx & 15;
    *(float4*)&Qs[row][dv * 4] = *(const float4*)(q + qbase + (size_t)row * D_ + dv * 4);
  }

  float m_i[4], l_i[4], o[4][4];
#pragma unroll
  for (int i = 0; i < 4; i++) {
    m_i[i] = NEG_INF; l_i[i] = 0.f;
#pragma unroll
    for (int j = 0; j < 4; j++) o[i][j] = 0.f;
  }

  const bool m_u8 = (*flag != 0);
  const unsigned char* m8 = (const unsigned char*)maskp;
  const int* m32 = (const int*)maskp;

  for (int nt = 0; nt < 8; nt++) {
    __syncthreads();
    const int n0 = nt * 64;
#pragma unroll
    for (int t = 0; t < 4; t++) {
      const int idx = tid + t * 256;
      const int j = idx >> 4, dv = idx & 15;
      const size_t base = ((size_t)b * N_ + n0 + j) * D_ + h * HD_ + dv * 4;
      const float4 kv4 = *(const float4*)(k + base);
      Kst[dv * 4 + 0][j] = kv4.x;
      Kst[dv * 4 + 1][j] = kv4.y;
      Kst[dv * 4 + 2][j] = kv4.z;
      Kst[dv * 4 + 3][j] = kv4.w;
      *(float4*)&Vs[j][dv * 4] = *(const float4*)(v + base);
    }
    if (tid < 64) {
      const int n = n0 + tid;
      const bool mv = m_u8 ? (m8[(size_t)b * N_ + n] != 0)
                           : (m32[(size_t)b * N_ + n] != 0);
      Msk[tid] = mv ? 0.f : NEG_INF;
    }
    __syncthreads();

    // ---- S = scale * Q K^T + mask  (4x4 per thread) ----
    float s[4][4];
#pragma unroll
    for (int i = 0; i < 4; i++)
#pragma unroll
      for (int j = 0; j < 4; j++) s[i][j] = 0.f;
#pragma unroll
    for (int d4 = 0; d4 < 16; d4++) {
      float qa[4][4], ka[4][4];
#pragma unroll
      for (int i = 0; i < 4; i++) {
        const float4 t = *(const float4*)&Qs[r0 + i][d4 * 4];
        qa[i][0] = t.x; qa[i][1] = t.y; qa[i][2] = t.z; qa[i][3] = t.w;
      }
#pragma unroll
      for (int dd = 0; dd < 4; dd++) {
        const float4 t = *(const float4*)&Kst[d4 * 4 + dd][c0];
        ka[dd][0] = t.x; ka[dd][1] = t.y; ka[dd][2] = t.z; ka[dd][3] = t.w;
      }
#pragma unroll
      for (int i = 0; i < 4; i++)
#pragma unroll
        for (int dd = 0; dd < 4; dd++)
#pragma unroll
          for (int j = 0; j < 4; j++)
            s[i][j] = fmaf(qa[i][dd], ka[dd][j], s[i][j]);
    }
    float msk_l[4];
    {
      const float4 t = *(const float4*)&Msk[c0];
      msk_l[0] = t.x; msk_l[1] = t.y; msk_l[2] = t.z; msk_l[3] = t.w;
    }
#pragma unroll
    for (int i = 0; i < 4; i++)
#pragma unroll
      for (int j = 0; j < 4; j++) s[i][j] = s[i][j] * 0.125f + msk_l[j];

    // ---- online softmax (rows split across 16 lanes) ----
#pragma unroll
    for (int i = 0; i < 4; i++) {
      float mx = fmaxf(fmaxf(s[i][0], s[i][1]), fmaxf(s[i][2], s[i][3]));
#pragma unroll
      for (int off = 1; off < 16; off <<= 1) mx = fmaxf(mx, __shfl_xor(mx, off, 16));
      const float mnew = fmaxf(m_i[i], mx);
      const float corr = (mnew == NEG_INF) ? 1.f : __expf(m_i[i] - mnew);
      float rsum = 0.f;
#pragma unroll
      for (int j = 0; j < 4; j++) {
        const float p = (mnew == NEG_INF) ? 0.f : __expf(s[i][j] - mnew);
        s[i][j] = p;
        rsum += p;
      }
#pragma unroll
      for (int off = 1; off < 16; off <<= 1) rsum += __shfl_xor(rsum, off, 16);
      l_i[i] = l_i[i] * corr + rsum;
      m_i[i] = mnew;
#pragma unroll
      for (int j = 0; j < 4; j++) o[i][j] *= corr;
    }

    // ---- O += P V  (P via in-wave shuffles) ----
    const int lsrc_base = (rg & 3) * 16;
#pragma unroll
    for (int j4 = 0; j4 < 16; j4++) {
      float va[4][4];
#pragma unroll
      for (int jj = 0; jj < 4; jj++) {
        const float4 t = *(const float4*)&Vs[j4 * 4 + jj][c0];
        va[jj][0] = t.x; va[jj][1] = t.y; va[jj][2] = t.z; va[jj][3] = t.w;
      }
#pragma unroll
      for (int jj = 0; jj < 4; jj++)
#pragma unroll
        for (int i = 0; i < 4; i++) {
          const float pj = __shfl(s[i][jj], lsrc_base + j4, 64);
#pragma unroll
          for (int cc = 0; cc < 4; cc++)
            o[i][cc] = fmaf(pj, va[jj][cc], o[i][cc]);
        }
    }
  }

  // ---- normalize + write (nan_to_num: all-masked row -> zeros) ----
#pragma unroll
  for (int i = 0; i < 4; i++) {
    const float inv = (l_i[i] > 0.f) ? (1.f / l_i[i]) : 0.f;
    float4 ov;
    ov.x = o[i][0] * inv; ov.y = o[i][1] * inv;
    ov.z = o[i][2] * inv; ov.w = o[i][3] * inv;
    const size_t row = (size_t)b * L_ + (size_t)qt * 64 + r0 + i;
    *(float4*)(ctx + row * D_ + h * HD_ + c0) = ov;
  }
}

// ---------------------------------------------------------------------------
extern "C" void kernel_launch(void* const* d_in, const int* in_sizes, int n_in,
                              void* d_out, int out_size, void* d_ws, size_t ws_size,
                              hipStream_t stream) {
  const float* text    = (const float*)d_in[0];
  const float* regions = (const float*)d_in[1];
  const void*  mask    = d_in[2];
  const float* Wq      = (const float*)d_in[3];
  const float* Wk      = (const float*)d_in[4];
  const float* Wv      = (const float*)d_in[5];
  const float* Wo      = (const float*)d_in[6];
  const float* bo      = (const float*)d_in[7];
  const float* gq      = (const float*)d_in[8];
  const float* bq      = (const float*)d_in[9];
  const float* gkv     = (const float*)d_in[10];
  const float* bkv     = (const float*)d_in[11];
  float* out = (float*)d_out;

  float* ws   = (float*)d_ws;
  float* qbuf = ws;                           // B*L*D (doubles as ctx)
  float* kbuf = qbuf + (size_t)B_ * L_ * D_;  // B*N*D
  float* vbuf = kbuf + (size_t)B_ * N_ * D_;  // B*N*D
  float* mu_t = vbuf + (size_t)B_ * N_ * D_;  // B*L
  float* rs_t = mu_t + B_ * L_;
  float* mu_r = rs_t + B_ * L_;               // B*N
  float* rs_r = mu_r + B_ * N_;
  int*   flag = (int*)(rs_r + B_ * N_);

  detect_mask_kernel<<<1, 256, 0, stream>>>((const unsigned char*)mask, flag);

  ln_stats_kernel<<<B_ * L_, 256, 0, stream>>>(text, mu_t, rs_t);
  ln_stats_kernel<<<B_ * N_, 256, 0, stream>>>(regions, mu_r, rs_r);

  // q = LN(text) @ Wq^T
  gemm_nt_kernel<true, 0><<<dim3(128, 8), 256, 0, stream>>>(
      text, Wq, qbuf, mu_t, rs_t, gq, bq, nullptr, nullptr);
  // k = LN(regions) @ Wk^T
  gemm_nt_kernel<true, 0><<<dim3(32, 8), 256, 0, stream>>>(
      regions, Wk, kbuf, mu_r, rs_r, gkv, bkv, nullptr, nullptr);
  // v = regions @ Wv^T
  gemm_nt_kernel<false, 0><<<dim3(32, 8), 256, 0, stream>>>(
      regions, Wv, vbuf, nullptr, nullptr, nullptr, nullptr, nullptr, nullptr);

  // attention (ctx written in-place over qbuf; each block reads exactly the
  // slice it later writes)
  attn_kernel<<<B_ * H_ * (L_ / 64), 256, 0, stream>>>(
      qbuf, kbuf, vbuf, mask, flag, qbuf);

  // out = text + ctx @ Wo^T + bo
  gemm_nt_kernel<false, 1><<<dim3(128, 8), 256, 0, stream>>>(
      qbuf, Wo, out, nullptr, nullptr, nullptr, nullptr, bo, text);
}

// Round 2
// 329.559 us; speedup vs baseline: 5.5426x; 5.5426x over previous
//
#include <hip/hip_runtime.h>

#define NEG_INF (-__builtin_inff())

typedef _Float16 half8 __attribute__((ext_vector_type(8)));
typedef _Float16 half4 __attribute__((ext_vector_type(4)));
typedef float f32x4 __attribute__((ext_vector_type(4)));

__device__ __forceinline__ void gload_lds16(const void* g, void* l) {
  __builtin_amdgcn_global_load_lds(
      (const __attribute__((address_space(1))) void*)g,
      (__attribute__((address_space(3))) void*)l, 16, 0, 0);
}

// ---------------------------------------------------------------------------
// Mask dtype detection: int32 0/1 has zero bytes at idx%4!=0; uint8 bool does
// not. All-zero mask degenerates identically either way.
// ---------------------------------------------------------------------------
__global__ __launch_bounds__(256) void detect_mask_kernel(
    const unsigned char* __restrict__ m, int* __restrict__ flag) {
  __shared__ int sany;
  if (threadIdx.x == 0) sany = 0;
  __syncthreads();
  int any = 0;
  for (int i = threadIdx.x; i < 8 * 512; i += 256)
    if ((i & 3) != 0 && m[i] != 0) any = 1;
  if (any) sany = 1;
  __syncthreads();
  if (threadIdx.x == 0) *flag = sany;  // 1 => uint8, 0 => int32
}

// ---------------------------------------------------------------------------
// Fused LayerNorm + fp16 cast. One block per row, D=1024.
// ---------------------------------------------------------------------------
__global__ __launch_bounds__(256) void ln_cast_kernel(
    const float* __restrict__ X, const float* __restrict__ ga,
    const float* __restrict__ be, _Float16* __restrict__ Y) {
  const int row = blockIdx.x;
  const int t = threadIdx.x;
  const float4 x = ((const float4*)(X + (size_t)row * 1024))[t];
  float s  = x.x + x.y + x.z + x.w;
  float ss = x.x * x.x + x.y * x.y + x.z * x.z + x.w * x.w;
#pragma unroll
  for (int off = 32; off > 0; off >>= 1) {
    s  += __shfl_down(s, off);
    ss += __shfl_down(ss, off);
  }
  __shared__ float red[8];
  __shared__ float smu, srs;
  if ((t & 63) == 0) { red[(t >> 6) * 2] = s; red[(t >> 6) * 2 + 1] = ss; }
  __syncthreads();
  if (t == 0) {
    const float S  = red[0] + red[2] + red[4] + red[6];
    const float SS = red[1] + red[3] + red[5] + red[7];
    const float mm = S * (1.f / 1024.f);
    const float vv = SS * (1.f / 1024.f) - mm * mm;
    smu = mm; srs = rsqrtf(vv + 1e-5f);
  }
  __syncthreads();
  const float mu = smu, rs = srs;
  const float4 g  = ((const float4*)ga)[t];
  const float4 bb = ((const float4*)be)[t];
  half4 y;
  y[0] = (_Float16)((x.x - mu) * rs * g.x + bb.x);
  y[1] = (_Float16)((x.y - mu) * rs * g.y + bb.y);
  y[2] = (_Float16)((x.z - mu) * rs * g.z + bb.z);
  y[3] = (_Float16)((x.w - mu) * rs * g.w + bb.w);
  ((half4*)(Y + (size_t)row * 1024))[t] = y;
}

// ---------------------------------------------------------------------------
// fp32 -> fp16 cast, 8 elements/thread.
// ---------------------------------------------------------------------------
__global__ __launch_bounds__(256) void cast_f2h_kernel(
    const float* __restrict__ X, _Float16* __restrict__ Y, int n8) {
  const int i = blockIdx.x * 256 + threadIdx.x;
  if (i >= n8) return;
  const float4 a  = ((const float4*)X)[i * 2];
  const float4 b2 = ((const float4*)X)[i * 2 + 1];
  half8 y;
  y[0] = (_Float16)a.x;  y[1] = (_Float16)a.y;
  y[2] = (_Float16)a.z;  y[3] = (_Float16)a.w;
  y[4] = (_Float16)b2.x; y[5] = (_Float16)b2.y;
  y[6] = (_Float16)b2.z; y[7] = (_Float16)b2.w;
  ((half8*)Y)[i] = y;
}

// ---------------------------------------------------------------------------
// Y = A @ W^T, fp16 inputs, MFMA 16x16x32_f16, K = 1024.
// 128x128 tile, BK=32, 256 threads (4 waves, each 64x64 output).
// Staging: global_load_lds width-16, linear [row][32] LDS (m97 pattern).
// EPI 0: fp16 out.  EPI 1: fp32 out + resid[row,col] + bias[col].
// ---------------------------------------------------------------------------
template <int EPI>
__global__ __launch_bounds__(256) void hgemm_nt(
    const _Float16* __restrict__ A, const _Float16* __restrict__ W,
    void* __restrict__ Yv, const float* __restrict__ bias,
    const float* __restrict__ resid) {
  __shared__ _Float16 As[4096];  // [128][32]
  __shared__ _Float16 Bs[4096];
  const int tid = threadIdx.x;
  const int bm = blockIdx.x, bn = blockIdx.y;
  const int wid = tid >> 6, lane = tid & 63;
  const int wr = wid >> 1, wc = wid & 1;
  const int l15 = lane & 15, lg = lane >> 4;

  f32x4 acc[4][4] = {};

  const int c0 = tid, c1 = tid + 256;  // 16B chunk ids (512 = 128 rows x 4)
  const _Float16* Ag0 = A + (size_t)(bm * 128 + (c0 >> 2)) * 1024 + (c0 & 3) * 8;
  const _Float16* Ag1 = A + (size_t)(bm * 128 + (c1 >> 2)) * 1024 + (c1 & 3) * 8;
  const _Float16* Bg0 = W + (size_t)(bn * 128 + (c0 >> 2)) * 1024 + (c0 & 3) * 8;
  const _Float16* Bg1 = W + (size_t)(bn * 128 + (c1 >> 2)) * 1024 + (c1 & 3) * 8;
  _Float16* Asw0 = &As[wid * 512];         // wave-uniform LDS base (+lane*16B HW)
  _Float16* Asw1 = &As[wid * 512 + 2048];
  _Float16* Bsw0 = &Bs[wid * 512];
  _Float16* Bsw1 = &Bs[wid * 512 + 2048];

  for (int kt = 0; kt < 1024; kt += 32) {
    __syncthreads();
    gload_lds16(Ag0 + kt, Asw0);
    gload_lds16(Ag1 + kt, Asw1);
    gload_lds16(Bg0 + kt, Bsw0);
    gload_lds16(Bg1 + kt, Bsw1);
    __syncthreads();
    half8 a[4], b[4];
#pragma unroll
    for (int m = 0; m < 4; m++)
      a[m] = *(const half8*)&As[(wr * 64 + m * 16 + l15) * 32 + lg * 8];
#pragma unroll
    for (int n = 0; n < 4; n++)
      b[n] = *(const half8*)&Bs[(wc * 64 + n * 16 + l15) * 32 + lg * 8];
#pragma unroll
    for (int m = 0; m < 4; m++)
#pragma unroll
      for (int n = 0; n < 4; n++)
        acc[m][n] = __builtin_amdgcn_mfma_f32_16x16x32_f16(a[m], b[n], acc[m][n], 0, 0, 0);
  }

  if (EPI == 0) {
    _Float16* Y = (_Float16*)Yv;
#pragma unroll
    for (int m = 0; m < 4; m++) {
      const int gr0 = bm * 128 + wr * 64 + m * 16 + lg * 4;
#pragma unroll
      for (int n = 0; n < 4; n++) {
        const int gc = bn * 128 + wc * 64 + n * 16 + l15;
#pragma unroll
        for (int r = 0; r < 4; r++)
          Y[(size_t)(gr0 + r) * 1024 + gc] = (_Float16)acc[m][n][r];
      }
    }
  } else {
    float* Y = (float*)Yv;
#pragma unroll
    for (int m = 0; m < 4; m++) {
      const int gr0 = bm * 128 + wr * 64 + m * 16 + lg * 4;
#pragma unroll
      for (int n = 0; n < 4; n++) {
        const int gc = bn * 128 + wc * 64 + n * 16 + l15;
        const float bv = bias[gc];
#pragma unroll
        for (int r = 0; r < 4; r++)
          Y[(size_t)(gr0 + r) * 1024 + gc] =
              acc[m][n][r] + bv + resid[(size_t)(gr0 + r) * 1024 + gc];
      }
    }
  }
}

// ---------------------------------------------------------------------------
// MFMA flash attention. Block = (b, head, 128 q-rows); 4 waves x 32 rows.
// K: LDS [64][64] linear, source-XOR-swizzled chunks (bank-uniform b128 reads).
// V: LDS transposed [64][72], chunk-swizzled by (d>>3).
// P: per-wave LDS [32][72] round-trip (C-frag layout -> A-frag layout).
// Online softmax in registers, 16-lane shfl_xor row reduces.
// Writes ctx over the q buffer (block-private rows/cols).
// ---------------------------------------------------------------------------
__global__ __launch_bounds__(256) void attn_mfma(
    const _Float16* __restrict__ q, const _Float16* __restrict__ kk,
    const _Float16* __restrict__ vv, const void* __restrict__ maskp,
    const int* __restrict__ flag, _Float16* __restrict__ ctx) {
  __shared__ _Float16 Ks[64 * 64];
  __shared__ _Float16 Vt[64 * 72];
  __shared__ _Float16 Pl[4][32][72];
  __shared__ float Msk[64];

  const int bid = blockIdx.x;
  const int qt = bid & 15;
  const int hh = (bid >> 4) & 15;
  const int b  = bid >> 8;
  const int tid = threadIdx.x;
  const int wid = tid >> 6, lane = tid & 63;
  const int l15 = lane & 15, lg = lane >> 4;
  const int g8 = lane >> 3, d8 = lane & 7;

  // Q fragments (A-layout): row = l15, k = lg*8+i
  half8 aq[2][2];
  {
    const size_t qrow0 = (size_t)b * 2048 + qt * 128 + wid * 32;
#pragma unroll
    for (int m = 0; m < 2; m++)
#pragma unroll
      for (int kg = 0; kg < 2; kg++)
        aq[m][kg] = *(const half8*)(q + (qrow0 + m * 16 + l15) * 1024 + hh * 64 + kg * 32 + lg * 8);
  }

  float mst[2][4], lst[2][4];
  f32x4 o[2][4] = {};
#pragma unroll
  for (int m = 0; m < 2; m++)
#pragma unroll
    for (int r = 0; r < 4; r++) { mst[m][r] = NEG_INF; lst[m][r] = 0.f; }

  const bool mu8 = (*flag != 0);
  const unsigned char* m8 = (const unsigned char*)maskp;
  const int* m32 = (const int*)maskp;

  for (int nt = 0; nt < 8; nt++) {
    __syncthreads();
    // ---- stage K (gload_lds, src-swizzled) + V (transposed, reg route) ----
#pragma unroll
    for (int hseg = 0; hseg < 2; hseg++) {
      const int n = hseg * 32 + wid * 8 + g8;       // n&7 == g8
      const int kc = d8 ^ g8;                        // source chunk for K
      const size_t grow = (size_t)b * 512 + nt * 64 + n;
      gload_lds16(kk + grow * 1024 + hh * 64 + kc * 8, &Ks[hseg * 2048 + wid * 512]);
      const half8 vr = *(const half8*)(vv + grow * 1024 + hh * 64 + d8 * 8);
      const int pos = ((n >> 3) ^ d8) & 7;           // key = d>>3 = d8
#pragma unroll
      for (int i = 0; i < 8; i++)
        Vt[(d8 * 8 + i) * 72 + pos * 8 + g8] = vr[i];
    }
    if (tid < 64) {
      const int n = nt * 64 + tid;
      const bool mv = mu8 ? (m8[(size_t)b * 512 + n] != 0)
                          : (m32[(size_t)b * 512 + n] != 0);
      Msk[tid] = mv ? 0.f : NEG_INF;
    }
    __syncthreads();

    // ---- S = Q K^T ----
    f32x4 s[2][4] = {};
#pragma unroll
    for (int kg = 0; kg < 2; kg++) {
      half8 bk[4];
#pragma unroll
      for (int nf = 0; nf < 4; nf++) {
        const int row = nf * 16 + l15;
        const int pos = (kg * 4 + lg) ^ (row & 7);
        bk[nf] = *(const half8*)&Ks[row * 64 + pos * 8];
      }
#pragma unroll
      for (int m = 0; m < 2; m++)
#pragma unroll
        for (int nf = 0; nf < 4; nf++)
          s[m][nf] = __builtin_amdgcn_mfma_f32_16x16x32_f16(aq[m][kg], bk[nf], s[m][nf], 0, 0, 0);
    }

    // ---- mask + scale ----
    float mskv[4];
#pragma unroll
    for (int nf = 0; nf < 4; nf++) mskv[nf] = Msk[nf * 16 + l15];
#pragma unroll
    for (int m = 0; m < 2; m++)
#pragma unroll
      for (int nf = 0; nf < 4; nf++)
#pragma unroll
        for (int r = 0; r < 4; r++)
          s[m][nf][r] = s[m][nf][r] * 0.125f + mskv[nf];

    // ---- online softmax (row = lg*4+r within m-frag; reduce over l15) ----
    float corr[2][4];
#pragma unroll
    for (int m = 0; m < 2; m++)
#pragma unroll
      for (int r = 0; r < 4; r++) {
        float mx = fmaxf(fmaxf(s[m][0][r], s[m][1][r]), fmaxf(s[m][2][r], s[m][3][r]));
#pragma unroll
        for (int off = 1; off < 16; off <<= 1) mx = fmaxf(mx, __shfl_xor(mx, off, 64));
        const float mnew = fmaxf(mst[m][r], mx);
        const float mc = fmaxf(mnew, -1e30f);
        const float cr = __expf(fmaxf(mst[m][r], -1e30f) - mc);
        float rsum = 0.f;
#pragma unroll
        for (int nf = 0; nf < 4; nf++) {
          const float p = __expf(s[m][nf][r] - mc);
          s[m][nf][r] = p;
          rsum += p;
        }
#pragma unroll
        for (int off = 1; off < 16; off <<= 1) rsum += __shfl_xor(rsum, off, 64);
        lst[m][r] = lst[m][r] * cr + rsum;
        mst[m][r] = mnew;
        corr[m][r] = cr;
      }
#pragma unroll
    for (int m = 0; m < 2; m++)
#pragma unroll
      for (int d = 0; d < 4; d++)
#pragma unroll
        for (int r = 0; r < 4; r++)
          o[m][d][r] *= corr[m][r];

    // ---- P -> LDS (fp16, A-frag friendly) ----
#pragma unroll
    for (int m = 0; m < 2; m++)
#pragma unroll
      for (int nf = 0; nf < 4; nf++)
#pragma unroll
        for (int r = 0; r < 4; r++)
          Pl[wid][m * 16 + lg * 4 + r][nf * 16 + l15] = (_Float16)s[m][nf][r];

    // ---- O += P V ----
#pragma unroll
    for (int ks = 0; ks < 2; ks++) {
      half8 pa[2], bv[4];
#pragma unroll
      for (int m = 0; m < 2; m++)
        pa[m] = *(const half8*)&Pl[wid][m * 16 + l15][ks * 32 + lg * 8];
#pragma unroll
      for (int df = 0; df < 4; df++) {
        const int row = df * 16 + l15;
        const int pos = (ks * 4 + lg) ^ (row >> 3);
        bv[df] = *(const half8*)&Vt[row * 72 + pos * 8];
      }
#pragma unroll
      for (int m = 0; m < 2; m++)
#pragma unroll
        for (int df = 0; df < 4; df++)
          o[m][df] = __builtin_amdgcn_mfma_f32_16x16x32_f16(pa[m], bv[df], o[m][df], 0, 0, 0);
    }
  }

  // ---- normalize + write ctx (all-masked rows -> zeros) ----
#pragma unroll
  for (int m = 0; m < 2; m++)
#pragma unroll
    for (int r = 0; r < 4; r++) {
      const float inv = (lst[m][r] > 0.f) ? (1.f / lst[m][r]) : 0.f;
      const size_t grow = (size_t)b * 2048 + qt * 128 + wid * 32 + m * 16 + lg * 4 + r;
#pragma unroll
      for (int df = 0; df < 4; df++)
        ctx[grow * 1024 + hh * 64 + df * 16 + l15] = (_Float16)(o[m][df][r] * inv);
    }
}

// ---------------------------------------------------------------------------
extern "C" void kernel_launch(void* const* d_in, const int* in_sizes, int n_in,
                              void* d_out, int out_size, void* d_ws, size_t ws_size,
                              hipStream_t stream) {
  const float* text    = (const float*)d_in[0];
  const float* regions = (const float*)d_in[1];
  const void*  mask    = d_in[2];
  const float* Wq      = (const float*)d_in[3];
  const float* Wk      = (const float*)d_in[4];
  const float* Wv      = (const float*)d_in[5];
  const float* Wo      = (const float*)d_in[6];
  const float* bo      = (const float*)d_in[7];
  const float* gq      = (const float*)d_in[8];
  const float* bq      = (const float*)d_in[9];
  const float* gkv     = (const float*)d_in[10];
  const float* bkv     = (const float*)d_in[11];

  _Float16* ws16 = (_Float16*)d_ws;
  _Float16* wq16 = ws16;                  // 1M halves each
  _Float16* wk16 = wq16 + 1048576;
  _Float16* wv16 = wk16 + 1048576;
  _Float16* wo16 = wv16 + 1048576;
  _Float16* at16 = wo16 + 1048576;        // 16.7M halves (LN text; reused for LN regions / raw regions)
  _Float16* q16  = at16 + 16777216;       // 16.7M (doubles as ctx)
  _Float16* k16  = q16 + 16777216;        // 4.2M
  _Float16* v16  = k16 + 4194304;         // 4.2M
  int* flag = (int*)(v16 + 4194304);

  detect_mask_kernel<<<1, 256, 0, stream>>>((const unsigned char*)mask, flag);

  cast_f2h_kernel<<<512, 256, 0, stream>>>(Wq, wq16, 131072);
  cast_f2h_kernel<<<512, 256, 0, stream>>>(Wk, wk16, 131072);
  cast_f2h_kernel<<<512, 256, 0, stream>>>(Wv, wv16, 131072);
  cast_f2h_kernel<<<512, 256, 0, stream>>>(Wo, wo16, 131072);

  // q = LN(text) @ Wq^T
  ln_cast_kernel<<<16384, 256, 0, stream>>>(text, gq, bq, at16);
  hgemm_nt<0><<<dim3(128, 8), 256, 0, stream>>>(at16, wq16, q16, nullptr, nullptr);

  // k = LN(regions) @ Wk^T   (at16 reused after q-GEMM consumed it)
  ln_cast_kernel<<<4096, 256, 0, stream>>>(regions, gkv, bkv, at16);
  hgemm_nt<0><<<dim3(32, 8), 256, 0, stream>>>(at16, wk16, k16, nullptr, nullptr);

  // v = regions @ Wv^T
  cast_f2h_kernel<<<2048, 256, 0, stream>>>(regions, at16 + 4194304, 524288);
  hgemm_nt<0><<<dim3(32, 8), 256, 0, stream>>>(at16 + 4194304, wv16, v16, nullptr, nullptr);

  // attention (ctx overwrites q16; block-private rows/cols)
  attn_mfma<<<2048, 256, 0, stream>>>(q16, k16, v16, mask, flag, q16);

  // out = text + ctx @ Wo^T + bo
  hgemm_nt<1><<<dim3(128, 8), 256, 0, stream>>>(q16, wo16, d_out, bo, text);
}